// Round 14
// baseline (331.354 us; speedup 1.0000x reference)
//
#include <hip/hip_runtime.h>

#define M_DIM 8192
#define N_DIM 6144
#define K_DIM 3072
#define NKT 96            // K / 32 K-tiles
#define NBK (K_DIM / 128) // 24 scale blocks along K

typedef __attribute__((ext_vector_type(8))) short short8;
typedef __attribute__((ext_vector_type(4))) float f32x4v;

// round-to-nearest-even f32->bf16, two packed into a u32
__device__ __forceinline__ unsigned int pk2bf(float a, float b) {
  unsigned int ua = __float_as_uint(a);
  unsigned int ub = __float_as_uint(b);
  ua = (ua + 0x7FFFu + ((ua >> 16) & 1u)) >> 16;
  ub = (ub + 0x7FFFu + ((ub >> 16) & 1u)) & 0xFFFF0000u;
  return ua | ub;
}

__global__ void cvt_x(const float* __restrict__ X, uint2* __restrict__ O, int n4) {
  int stride = gridDim.x * blockDim.x;
  for (int i = blockIdx.x * blockDim.x + threadIdx.x; i < n4; i += stride) {
    float4 v = ((const float4*)X)[i];
    O[i] = make_uint2(pk2bf(v.x, v.y), pk2bf(v.z, v.w));
  }
}

__global__ void cvt_w(const float* __restrict__ W, const float* __restrict__ S,
                      uint2* __restrict__ O, int n4) {
  int stride = gridDim.x * blockDim.x;
  for (int i = blockIdx.x * blockDim.x + threadIdx.x; i < n4; i += stride) {
    unsigned int e = (unsigned int)i * 4u;
    unsigned int n = e / K_DIM;
    unsigned int k = e - n * K_DIM;
    float s = S[(n >> 7) * NBK + (k >> 7)];
    float4 v = ((const float4*)W)[i];
    O[i] = make_uint2(pk2bf(v.x * s, v.y * s), pk2bf(v.z * s, v.w * s));
  }
}

__device__ __forceinline__ void gload16(const unsigned short* g, unsigned short* l) {
  __builtin_amdgcn_global_load_lds(
      (const __attribute__((address_space(1))) void*)g,
      (__attribute__((address_space(3))) void*)l, 16, 0, 0);
}

// 256x256 tile, BK=32, ring-4 LDS slots (128 KB), SHADOWED-READ schedule:
// body t = {vmcnt(4)+bar; stage t+3; QUAD1 16 MFMA (regs from last body —
// no lgkm dep, issues immediately); sched_barrier; 12 reads (aH slot t
// FIRST — quad2's operands, counted-lgkm-waitable; then b+aL of slot t+1);
// QUAD2 16 MFMA (aH)}. All LDS reads execute under MFMA-drain shadows;
// no read gates a barrier. R13's null showed reads placed BEFORE the
// cluster serialize (conservative wait placement); R12's +gain came from
// the one read group placed after — this generalizes it.
// vmcnt(4) at body start: outstanding = stages t+1,t+2 (8 loads); retiring
// to 4 guarantees slot t+1 staged (t+2's 4 may fly). Stage slot
// (t+3)&3=(t-1)&3: its readers (body t-1's aH) consumed by t-1's quad2.
// LDS layout: row-major 64B rows, quad-local XOR swizzle (conflict-free).
// NOTE: ~250 unified VGPR+AGPR/wave; min-waves MUST stay 2 (R8: 4 ms).
__global__ __launch_bounds__(512, 2) void gemm_ring(
    const unsigned short* __restrict__ Xb, const unsigned short* __restrict__ Wb,
    float* __restrict__ Y) {
  extern __shared__ unsigned short lds[];   // As[4][8192] ++ Bs[4][8192] = 128 KB
  unsigned short* As = lds;
  unsigned short* Bs = lds + 32768;

  // XCD-aware mapping: 768 blocks = 8 XCD x 96; each XCD owns 4 bm-panels x 24 bn
  int bid = blockIdx.x;
  int c = bid & 7;
  int j = bid >> 3;                 // 0..95
  int bm = c * 4 + (j / 24);        // 0..31
  int bn = j % 24;                  // 0..23

  int tid = threadIdx.x;
  int lane = tid & 63;
  int wr = (tid >> 6) >> 2;         // 0..1  (wave M row)
  int wc = (tid >> 6) & 3;          // 0..3  (wave N col)

  // staging: thread t covers rows (t>>2)+{0,128}, 16B chunk ((t&3) ^ ((t>>3)&3))
  int s_row = tid >> 2;                        // 0..127
  int s_q   = (tid & 3) ^ ((tid >> 3) & 3);    // swizzled source chunk
  const unsigned short* Xg = Xb + ((size_t)bm * 256 + s_row) * K_DIM + s_q * 8;
  const unsigned short* Wg = Wb + ((size_t)bn * 256 + s_row) * K_DIM + s_q * 8;
  unsigned short* lax = As + tid * 8;       // linear LDS dest (uniform + lane*16B)
  unsigned short* lbx = Bs + tid * 8;

  // fragment read bases: row r = lane&15 (+16 per frag), chunk (lane>>4)^((lane>>1)&3)
  int fr = lane & 15;
  int fq = (lane >> 4) ^ ((lane >> 1) & 3);
  const unsigned short* Ab = As + ((wr * 128 + fr) << 5) + (fq << 3);
  const unsigned short* Bb = Bs + ((wc * 64 + fr) << 5) + (fq << 3);

#define STAGE(t) { int _sl = ((t) & 3) * 8192;                                  \
    const unsigned short* _xp = Xg + (size_t)(t) * 32;                          \
    const unsigned short* _wp = Wg + (size_t)(t) * 32;                          \
    gload16(_xp, lax + _sl);                                                    \
    gload16(_xp + (size_t)128 * K_DIM, lax + _sl + 4096);                       \
    gload16(_wp, lbx + _sl);                                                    \
    gload16(_wp + (size_t)128 * K_DIM, lbx + _sl + 4096); }

  f32x4v acc[8][4];
#pragma unroll
  for (int m = 0; m < 8; ++m)
#pragma unroll
    for (int n = 0; n < 4; ++n) acc[m][n] = (f32x4v)0.0f;

  short8 aL0[4], aL1[4], b0v[4], b1v[4];

  STAGE(0); STAGE(1); STAGE(2);   // 12 loads in flight
  asm volatile("s_waitcnt vmcnt(8)\n\ts_barrier" ::: "memory");  // slot 0 landed (all waves)
#pragma unroll
  for (int n = 0; n < 4; ++n)
    b0v[n] = *(const short8*)(Bb + n * 512);      // b(0)
#pragma unroll
  for (int m = 0; m < 4; ++m)
    aL0[m] = *(const short8*)(Ab + m * 512);      // aLO(0)

  // BODY(t): see header comment. ALC/BC preloaded last body; AH read here.
#define BODY(T, VM, DOSTAGE, DONEXT, ALC, BC, ALN, BN_) {                       \
    asm volatile("s_waitcnt vmcnt(" #VM ")\n\ts_barrier" ::: "memory");         \
    if (DOSTAGE) STAGE((T) + 3);                                                \
    int sl = ((T) & 3) * 8192;                                                  \
    int sln = (((T) + 1) & 3) * 8192;                                           \
    short8 aH[4];                                                               \
    __builtin_amdgcn_s_setprio(1);                                              \
    _Pragma("unroll") for (int m = 0; m < 4; ++m)                               \
      _Pragma("unroll") for (int n = 0; n < 4; ++n)                             \
        acc[m][n] = __builtin_amdgcn_mfma_f32_16x16x32_bf16(ALC[m], BC[n], acc[m][n], 0, 0, 0); \
    __builtin_amdgcn_s_setprio(0);                                              \
    __builtin_amdgcn_sched_barrier(0);                                          \
    _Pragma("unroll") for (int m = 0; m < 4; ++m)                               \
      aH[m] = *(const short8*)(Ab + sl + (m + 4) * 512);                        \
    if (DONEXT) {                                                               \
      _Pragma("unroll") for (int n = 0; n < 4; ++n)                             \
        BN_[n] = *(const short8*)(Bb + sln + n * 512);                          \
      _Pragma("unroll") for (int m = 0; m < 4; ++m)                             \
        ALN[m] = *(const short8*)(Ab + sln + m * 512);                          \
    }                                                                           \
    __builtin_amdgcn_s_setprio(1);                                              \
    _Pragma("unroll") for (int m = 0; m < 4; ++m)                               \
      _Pragma("unroll") for (int n = 0; n < 4; ++n)                             \
        acc[m + 4][n] = __builtin_amdgcn_mfma_f32_16x16x32_bf16(aH[m], BC[n], acc[m + 4][n], 0, 0, 0); \
    __builtin_amdgcn_s_setprio(0); }

  for (int tt = 0; tt < 92; tt += 4) {   // t = 0..91, stages 3..94
    BODY(tt + 0, 4, 1, 1, aL0, b0v, aL1, b1v);
    BODY(tt + 1, 4, 1, 1, aL1, b1v, aL0, b0v);
    BODY(tt + 2, 4, 1, 1, aL0, b0v, aL1, b1v);
    BODY(tt + 3, 4, 1, 1, aL1, b1v, aL0, b0v);
  }
  BODY(92, 4, 1, 1, aL0, b0v, aL1, b1v);   // stages 95; reads slot 93
  BODY(93, 4, 0, 1, aL1, b1v, aL0, b0v);   // reads slot 94
  BODY(94, 0, 0, 1, aL0, b0v, aL1, b1v);   // vmcnt(0): slot 95 landed
  BODY(95, 0, 0, 0, aL1, b1v, aL0, b0v);
#undef BODY
#undef STAGE

  // C/D layout: ncol = lane&15, mrow = (lane>>4)*4 + reg
  int mrow0 = bm * 256 + wr * 128 + ((lane >> 4) << 2);
  int ncol0 = bn * 256 + wc * 64 + (lane & 15);
#pragma unroll
  for (int m = 0; m < 8; ++m)
#pragma unroll
    for (int n = 0; n < 4; ++n)
#pragma unroll
      for (int r = 0; r < 4; ++r)
        Y[(size_t)(mrow0 + m * 16 + r) * N_DIM + ncol0 + n * 16] = acc[m][n][r];
}

// ================= fallback (R1 kernel) if ws too small =================
#define BM 128
#define BN 128
#define NTN (N_DIM / BN)
#define NK2 (K_DIM / 64)
__global__ __launch_bounds__(256, 2) void dq_gemm(
    const float* __restrict__ X, const float* __restrict__ W,
    const float* __restrict__ S, float* __restrict__ Y) {
  __shared__ unsigned short As[BM * 64];
  __shared__ unsigned short Bs[BN * 64];
  int bid = blockIdx.x;
  int cpx = gridDim.x >> 3;
  int wg = (bid & 7) * cpx + (bid >> 3);
  int bm = wg / NTN, bn = wg - (wg / NTN) * NTN;
  int tid = threadIdx.x, lane = tid & 63, wave = tid >> 6;
  int wm = (wave >> 1) << 6, wn = (wave & 1) << 6;
  const float* Xg = X + (size_t)bm * BM * K_DIM;
  const float* Wg = W + (size_t)bn * BN * K_DIM;
  int r0 = tid >> 4, c4 = tid & 15;
  f32x4v acc[4][4];
#pragma unroll
  for (int i = 0; i < 4; ++i)
#pragma unroll
    for (int jj = 0; jj < 4; ++jj) acc[i][jj] = (f32x4v)0.0f;
  float4 xa[8], xb[8];
#pragma unroll
  for (int i = 0; i < 8; ++i) xa[i] = *(const float4*)(Xg + (size_t)(i * 16 + r0) * K_DIM + c4 * 4);
#pragma unroll
  for (int i = 0; i < 8; ++i) xb[i] = *(const float4*)(Wg + (size_t)(i * 16 + r0) * K_DIM + c4 * 4);
  char* Ac = (char*)As; char* Bc = (char*)Bs;
  int sw = (lane & 7) << 4, kb = (lane >> 4) << 4;
  int rA = wm + (lane & 15), rB = wn + (lane & 15);
  for (int kk = 0; kk < NK2; ++kk) {
    float s = S[bn * NBK + (kk >> 1)];
    __syncthreads();
#pragma unroll
    for (int i = 0; i < 8; ++i) {
      int row = i * 16 + r0;
      int off = row * 128 + ((c4 * 8) ^ ((row & 7) << 4));
      *(uint2*)(Ac + off) = make_uint2(pk2bf(xa[i].x, xa[i].y), pk2bf(xa[i].z, xa[i].w));
      *(uint2*)(Bc + off) = make_uint2(pk2bf(xb[i].x * s, xb[i].y * s), pk2bf(xb[i].z * s, xb[i].w * s));
    }
    __syncthreads();
    if (kk + 1 < NK2) {
      const float* Xn = Xg + (size_t)(kk + 1) * 64;
      const float* Wn = Wg + (size_t)(kk + 1) * 64;
#pragma unroll
      for (int i = 0; i < 8; ++i) xa[i] = *(const float4*)(Xn + (size_t)(i * 16 + r0) * K_DIM + c4 * 4);
#pragma unroll
      for (int i = 0; i < 8; ++i) xb[i] = *(const float4*)(Wn + (size_t)(i * 16 + r0) * K_DIM + c4 * 4);
    }
    short8 a0[4], a1[4], b0[4], b1[4];
#pragma unroll
    for (int i = 0; i < 4; ++i) {
      int rowA = rA + i * 16, rowB = rB + i * 16;
      a0[i] = *(const short8*)(Ac + rowA * 128 + (kb ^ sw));
      a1[i] = *(const short8*)(Ac + rowA * 128 + ((kb + 64) ^ sw));
      b0[i] = *(const short8*)(Bc + rowB * 128 + (kb ^ sw));
      b1[i] = *(const short8*)(Bc + rowB * 128 + ((kb + 64) ^ sw));
    }
#pragma unroll
    for (int i = 0; i < 4; ++i)
#pragma unroll
      for (int jj = 0; jj < 4; ++jj) {
        acc[i][jj] = __builtin_amdgcn_mfma_f32_16x16x32_bf16(a0[i], b0[jj], acc[i][jj], 0, 0, 0);
        acc[i][jj] = __builtin_amdgcn_mfma_f32_16x16x32_bf16(a1[i], b1[jj], acc[i][jj], 0, 0, 0);
      }
  }
  int mrow0 = bm * BM + wm + ((lane >> 4) << 2);
  int ncol0 = bn * BN + wn + (lane & 15);
#pragma unroll
  for (int i = 0; i < 4; ++i)
#pragma unroll
    for (int jj = 0; jj < 4; ++jj)
#pragma unroll
      for (int r = 0; r < 4; ++r)
        Y[(size_t)(mrow0 + i * 16 + r) * N_DIM + ncol0 + jj * 16] = acc[i][jj][r];
}

extern "C" void kernel_launch(void* const* d_in, const int* in_sizes, int n_in,
                              void* d_out, int out_size, void* d_ws, size_t ws_size,
                              hipStream_t stream) {
  const float* X = (const float*)d_in[0];
  const float* W = (const float*)d_in[1];
  const float* S = (const float*)d_in[2];
  float* Y = (float*)d_out;

  const size_t xb_bytes = (size_t)M_DIM * K_DIM * 2;
  const size_t wb_bytes = (size_t)N_DIM * K_DIM * 2;
  if (ws_size >= xb_bytes + wb_bytes) {
    unsigned short* Xbf = (unsigned short*)d_ws;
    unsigned short* Wbf = (unsigned short*)((char*)d_ws + xb_bytes);
    cvt_x<<<2048, 256, 0, stream>>>(X, (uint2*)Xbf, M_DIM * K_DIM / 4);
    cvt_w<<<2048, 256, 0, stream>>>(W, S, (uint2*)Wbf, N_DIM * K_DIM / 4);
    static int attr_set = 0;
    if (!attr_set) {
      hipFuncSetAttribute((const void*)gemm_ring,
                          hipFuncAttributeMaxDynamicSharedMemorySize, 131072);
      attr_set = 1;
    }
    dim3 grid((M_DIM / 256) * (N_DIM / 256));  // 768
    gemm_ring<<<grid, 512, 131072, stream>>>(Xbf, Wbf, Y);
  } else {
    dim3 grid((M_DIM / BM) * (N_DIM / BN));
    dq_gemm<<<grid, 256, 0, stream>>>(X, W, S, Y);
  }
}

// Round 15
// 324.358 us; speedup vs baseline: 1.0216x; 1.0216x over previous
//
#include <hip/hip_runtime.h>

#define M_DIM 8192
#define N_DIM 6144
#define K_DIM 3072
#define NKT 96            // K / 32 K-tiles
#define NBK (K_DIM / 128) // 24 scale blocks along K

typedef __attribute__((ext_vector_type(8))) short short8;
typedef __attribute__((ext_vector_type(4))) float f32x4v;

// round-to-nearest-even f32->bf16, two packed into a u32
__device__ __forceinline__ unsigned int pk2bf(float a, float b) {
  unsigned int ua = __float_as_uint(a);
  unsigned int ub = __float_as_uint(b);
  ua = (ua + 0x7FFFu + ((ua >> 16) & 1u)) >> 16;
  ub = (ub + 0x7FFFu + ((ub >> 16) & 1u)) & 0xFFFF0000u;
  return ua | ub;
}

// fused conversion: first nx4 float4-units are X (plain convert), the next
// nw4 units are W (dequant-scaled). One launch, grid-stride, both BW-bound.
__global__ void cvt_xw(const float* __restrict__ X, const float* __restrict__ W,
                       const float* __restrict__ S, uint2* __restrict__ OX,
                       uint2* __restrict__ OW, int nx4, int ntot) {
  int stride = gridDim.x * blockDim.x;
  for (int i = blockIdx.x * blockDim.x + threadIdx.x; i < ntot; i += stride) {
    if (i < nx4) {
      float4 v = ((const float4*)X)[i];
      OX[i] = make_uint2(pk2bf(v.x, v.y), pk2bf(v.z, v.w));
    } else {
      int u = i - nx4;
      unsigned int e = (unsigned int)u * 4u;
      unsigned int n = e / K_DIM;
      unsigned int k = e - n * K_DIM;
      float s = S[(n >> 7) * NBK + (k >> 7)];
      float4 v = ((const float4*)W)[u];
      OW[u] = make_uint2(pk2bf(v.x * s, v.y * s), pk2bf(v.z * s, v.w * s));
    }
  }
}

__device__ __forceinline__ void gload16(const unsigned short* g, unsigned short* l) {
  __builtin_amdgcn_global_load_lds(
      (const __attribute__((address_space(1))) void*)g,
      (__attribute__((address_space(3))) void*)l, 16, 0, 0);
}

// 256x256 tile, BK=32, ring-4 LDS slots (128 KB) — R5's schedule plus the
// R12 B-fragment software pipeline (the verified best of 7 schedule variants:
// R5 280us, R7 297, R9 317, R10 323, R11 322, R12 274, R13 277, R14 283).
// Body t: {vmcnt(4)+barrier; stage t+3; 8 A-frag reads slot t; MFMA m=0..3
// with b(t) [read last body]; sched_barrier; read b(t+1) from slot t+1
// (under MFMA shadow); MFMA m=4..7}.
// vmcnt(4): outstanding = stages t+1,t+2 (8 loads); retiring to 4 guarantees
// slot t+1 staged. Stage slot (t+3)&3=(t-1)&3: its readers (body t-1)
// completed before this barrier. Quad-local XOR swizzle (conflict-free,
// SQ_LDS_BANK_CONFLICT=0 measured): chunk q stored at q ^ ((row>>1)&3).
// NOTE: ~250 unified VGPR+AGPR/wave; launch_bounds min-waves MUST stay 2
// (R8: forcing 4 waves/EU spilled acc -> 4 ms, WRITE_SIZE 9.9 GB).
__global__ __launch_bounds__(512, 2) void gemm_ring(
    const unsigned short* __restrict__ Xb, const unsigned short* __restrict__ Wb,
    float* __restrict__ Y) {
  extern __shared__ unsigned short lds[];   // As[4][8192] ++ Bs[4][8192] = 128 KB
  unsigned short* As = lds;
  unsigned short* Bs = lds + 32768;

  // XCD-aware mapping: 768 blocks = 8 XCD x 96; each XCD owns 4 bm-panels x 24 bn
  int bid = blockIdx.x;
  int c = bid & 7;
  int j = bid >> 3;                 // 0..95
  int bm = c * 4 + (j / 24);        // 0..31
  int bn = j % 24;                  // 0..23

  int tid = threadIdx.x;
  int lane = tid & 63;
  int wr = (tid >> 6) >> 2;         // 0..1  (wave M row)
  int wc = (tid >> 6) & 3;          // 0..3  (wave N col)

  // staging: thread t covers rows (t>>2)+{0,128}, 16B chunk ((t&3) ^ ((t>>3)&3))
  int s_row = tid >> 2;                        // 0..127
  int s_q   = (tid & 3) ^ ((tid >> 3) & 3);    // swizzled source chunk
  const unsigned short* Xg = Xb + ((size_t)bm * 256 + s_row) * K_DIM + s_q * 8;
  const unsigned short* Wg = Wb + ((size_t)bn * 256 + s_row) * K_DIM + s_q * 8;
  unsigned short* lax = As + tid * 8;       // linear LDS dest (uniform + lane*16B)
  unsigned short* lbx = Bs + tid * 8;

  // fragment read bases: row r = lane&15 (+16 per frag), chunk (lane>>4)^((lane>>1)&3)
  int fr = lane & 15;
  int fq = (lane >> 4) ^ ((lane >> 1) & 3);
  const unsigned short* Ab = As + ((wr * 128 + fr) << 5) + (fq << 3);
  const unsigned short* Bb = Bs + ((wc * 64 + fr) << 5) + (fq << 3);

#define STAGE(t) { int _sl = ((t) & 3) * 8192;                                  \
    const unsigned short* _xp = Xg + (size_t)(t) * 32;                          \
    const unsigned short* _wp = Wg + (size_t)(t) * 32;                          \
    gload16(_xp, lax + _sl);                                                    \
    gload16(_xp + (size_t)128 * K_DIM, lax + _sl + 4096);                       \
    gload16(_wp, lbx + _sl);                                                    \
    gload16(_wp + (size_t)128 * K_DIM, lbx + _sl + 4096); }

  f32x4v acc[8][4];
#pragma unroll
  for (int m = 0; m < 8; ++m)
#pragma unroll
    for (int n = 0; n < 4; ++n) acc[m][n] = (f32x4v)0.0f;

  short8 bA[4], bB[4];

  STAGE(0); STAGE(1); STAGE(2);   // 12 loads in flight
  asm volatile("s_waitcnt vmcnt(8)\n\ts_barrier" ::: "memory");  // slot 0 landed (all waves)
#pragma unroll
  for (int n = 0; n < 4; ++n)
    bA[n] = *(const short8*)(Bb + n * 512);   // B-frags for tile 0

  // BODY(t): vmcnt(VM)+barrier; stage t+3; read 8 A-frags slot t;
  // MFMA m=0..3 with CONS; [sched_barrier] read NXT B-frags from slot t+1
  // (under MFMA shadow); MFMA m=4..7.
#define BODY(T, VM, DOSTAGE, DOBN, CONS, NXT) {                                 \
    asm volatile("s_waitcnt vmcnt(" #VM ")\n\ts_barrier" ::: "memory");         \
    if (DOSTAGE) STAGE((T) + 3);                                                \
    int sl = ((T) & 3) * 8192;                                                  \
    int sln = (((T) + 1) & 3) * 8192;                                           \
    short8 a[8];                                                                \
    _Pragma("unroll") for (int m = 0; m < 8; ++m)                               \
      a[m] = *(const short8*)(Ab + sl + m * 512);                               \
    __builtin_amdgcn_s_setprio(1);                                              \
    _Pragma("unroll") for (int m = 0; m < 4; ++m)                               \
      _Pragma("unroll") for (int n = 0; n < 4; ++n)                             \
        acc[m][n] = __builtin_amdgcn_mfma_f32_16x16x32_bf16(a[m], CONS[n], acc[m][n], 0, 0, 0); \
    __builtin_amdgcn_sched_barrier(0);                                          \
    if (DOBN) { _Pragma("unroll") for (int n = 0; n < 4; ++n)                   \
      NXT[n] = *(const short8*)(Bb + sln + n * 512); }                          \
    _Pragma("unroll") for (int m = 4; m < 8; ++m)                               \
      _Pragma("unroll") for (int n = 0; n < 4; ++n)                             \
        acc[m][n] = __builtin_amdgcn_mfma_f32_16x16x32_bf16(a[m], CONS[n], acc[m][n], 0, 0, 0); \
    __builtin_amdgcn_s_setprio(0); }

  for (int tt = 0; tt < 92; tt += 4) {   // t = 0..91, stages 3..94
    BODY(tt + 0, 4, 1, 1, bA, bB);
    BODY(tt + 1, 4, 1, 1, bB, bA);
    BODY(tt + 2, 4, 1, 1, bA, bB);
    BODY(tt + 3, 4, 1, 1, bB, bA);
  }
  BODY(92, 4, 1, 1, bA, bB);   // stages 95; reads b(93)
  BODY(93, 4, 0, 1, bB, bA);   // reads b(94)
  BODY(94, 0, 0, 1, bA, bB);   // vmcnt(0): slot 95 landed; reads b(95)
  BODY(95, 0, 0, 0, bB, bA);
#undef BODY
#undef STAGE

  // C/D layout: ncol = lane&15, mrow = (lane>>4)*4 + reg
  int mrow0 = bm * 256 + wr * 128 + ((lane >> 4) << 2);
  int ncol0 = bn * 256 + wc * 64 + (lane & 15);
#pragma unroll
  for (int m = 0; m < 8; ++m)
#pragma unroll
    for (int n = 0; n < 4; ++n)
#pragma unroll
      for (int r = 0; r < 4; ++r)
        Y[(size_t)(mrow0 + m * 16 + r) * N_DIM + ncol0 + n * 16] = acc[m][n][r];
}

// ================= fallback (R1 kernel) if ws too small =================
#define BM 128
#define BN 128
#define NTN (N_DIM / BN)
#define NK2 (K_DIM / 64)
__global__ __launch_bounds__(256, 2) void dq_gemm(
    const float* __restrict__ X, const float* __restrict__ W,
    const float* __restrict__ S, float* __restrict__ Y) {
  __shared__ unsigned short As[BM * 64];
  __shared__ unsigned short Bs[BN * 64];
  int bid = blockIdx.x;
  int cpx = gridDim.x >> 3;
  int wg = (bid & 7) * cpx + (bid >> 3);
  int bm = wg / NTN, bn = wg - (wg / NTN) * NTN;
  int tid = threadIdx.x, lane = tid & 63, wave = tid >> 6;
  int wm = (wave >> 1) << 6, wn = (wave & 1) << 6;
  const float* Xg = X + (size_t)bm * BM * K_DIM;
  const float* Wg = W + (size_t)bn * BN * K_DIM;
  int r0 = tid >> 4, c4 = tid & 15;
  f32x4v acc[4][4];
#pragma unroll
  for (int i = 0; i < 4; ++i)
#pragma unroll
    for (int jj = 0; jj < 4; ++jj) acc[i][jj] = (f32x4v)0.0f;
  float4 xa[8], xb[8];
#pragma unroll
  for (int i = 0; i < 8; ++i) xa[i] = *(const float4*)(Xg + (size_t)(i * 16 + r0) * K_DIM + c4 * 4);
#pragma unroll
  for (int i = 0; i < 8; ++i) xb[i] = *(const float4*)(Wg + (size_t)(i * 16 + r0) * K_DIM + c4 * 4);
  char* Ac = (char*)As; char* Bc = (char*)Bs;
  int sw = (lane & 7) << 4, kb = (lane >> 4) << 4;
  int rA = wm + (lane & 15), rB = wn + (lane & 15);
  for (int kk = 0; kk < NK2; ++kk) {
    float s = S[bn * NBK + (kk >> 1)];
    __syncthreads();
#pragma unroll
    for (int i = 0; i < 8; ++i) {
      int row = i * 16 + r0;
      int off = row * 128 + ((c4 * 8) ^ ((row & 7) << 4));
      *(uint2*)(Ac + off) = make_uint2(pk2bf(xa[i].x, xa[i].y), pk2bf(xa[i].z, xa[i].w));
      *(uint2*)(Bc + off) = make_uint2(pk2bf(xb[i].x * s, xb[i].y * s), pk2bf(xb[i].z * s, xb[i].w * s));
    }
    __syncthreads();
    if (kk + 1 < NK2) {
      const float* Xn = Xg + (size_t)(kk + 1) * 64;
      const float* Wn = Wg + (size_t)(kk + 1) * 64;
#pragma unroll
      for (int i = 0; i < 8; ++i) xa[i] = *(const float4*)(Xn + (size_t)(i * 16 + r0) * K_DIM + c4 * 4);
#pragma unroll
      for (int i = 0; i < 8; ++i) xb[i] = *(const float4*)(Wn + (size_t)(i * 16 + r0) * K_DIM + c4 * 4);
    }
    short8 a0[4], a1[4], b0[4], b1[4];
#pragma unroll
    for (int i = 0; i < 4; ++i) {
      int rowA = rA + i * 16, rowB = rB + i * 16;
      a0[i] = *(const short8*)(Ac + rowA * 128 + (kb ^ sw));
      a1[i] = *(const short8*)(Ac + rowA * 128 + ((kb + 64) ^ sw));
      b0[i] = *(const short8*)(Bc + rowB * 128 + (kb ^ sw));
      b1[i] = *(const short8*)(Bc + rowB * 128 + ((kb + 64) ^ sw));
    }
#pragma unroll
    for (int i = 0; i < 4; ++i)
#pragma unroll
      for (int jj = 0; jj < 4; ++jj) {
        acc[i][jj] = __builtin_amdgcn_mfma_f32_16x16x32_bf16(a0[i], b0[jj], acc[i][jj], 0, 0, 0);
        acc[i][jj] = __builtin_amdgcn_mfma_f32_16x16x32_bf16(a1[i], b1[jj], acc[i][jj], 0, 0, 0);
      }
  }
  int mrow0 = bm * BM + wm + ((lane >> 4) << 2);
  int ncol0 = bn * BN + wn + (lane & 15);
#pragma unroll
  for (int i = 0; i < 4; ++i)
#pragma unroll
    for (int jj = 0; jj < 4; ++jj)
#pragma unroll
      for (int r = 0; r < 4; ++r)
        Y[(size_t)(mrow0 + i * 16 + r) * N_DIM + ncol0 + jj * 16] = acc[i][jj][r];
}

extern "C" void kernel_launch(void* const* d_in, const int* in_sizes, int n_in,
                              void* d_out, int out_size, void* d_ws, size_t ws_size,
                              hipStream_t stream) {
  const float* X = (const float*)d_in[0];
  const float* W = (const float*)d_in[1];
  const float* S = (const float*)d_in[2];
  float* Y = (float*)d_out;

  const size_t xb_bytes = (size_t)M_DIM * K_DIM * 2;
  const size_t wb_bytes = (size_t)N_DIM * K_DIM * 2;
  if (ws_size >= xb_bytes + wb_bytes) {
    unsigned short* Xbf = (unsigned short*)d_ws;
    unsigned short* Wbf = (unsigned short*)((char*)d_ws + xb_bytes);
    int nx4 = M_DIM * K_DIM / 4;   // 6291456
    int nw4 = N_DIM * K_DIM / 4;   // 4718592
    cvt_xw<<<2048, 256, 0, stream>>>(X, W, S, (uint2*)Xbf, (uint2*)Wbf,
                                     nx4, nx4 + nw4);
    static int attr_set = 0;
    if (!attr_set) {
      hipFuncSetAttribute((const void*)gemm_ring,
                          hipFuncAttributeMaxDynamicSharedMemorySize, 131072);
      attr_set = 1;
    }
    dim3 grid((M_DIM / 256) * (N_DIM / 256));  // 768
    gemm_ring<<<grid, 512, 131072, stream>>>(Xbf, Wbf, Y);
  } else {
    dim3 grid((M_DIM / BM) * (N_DIM / BN));
    dq_gemm<<<grid, 256, 0, stream>>>(X, W, S, Y);
  }
}